// Round 1
// baseline (198.535 us; speedup 1.0000x reference)
//
#include <hip/hip_runtime.h>
#include <stdint.h>

#define NROWS 2048
#define DDIM  9216
#define NTMAX 16                 // max 128-tiles per dim (2048/128)
#define NTRI  136                // NTMAX*(NTMAX+1)/2 triangle tiles
#define SLICES 16
#define KSLICE (DDIM / SLICES)   // 576
#define BK 32

typedef unsigned short u16;
typedef __bf16 bf16x8 __attribute__((ext_vector_type(8)));
typedef float  f32x4  __attribute__((ext_vector_type(4)));

// ws layout (bytes):
//   [0]        int   cnt        (active-row count)
//   [4]        float sq_sum     (raw sum of c^2)
//   [256 ..)   float C[NTRI][128][128]   (8,912,896 B) -- zeroed each call
//   [NF_OFF..) u16   nf[2048][9216]      (37,748,736 B)
#define C_OFF   256
#define C_BYTES (NTRI * 128 * 128 * 4)
#define ZERO_BYTES (C_OFF + C_BYTES)          // 8,913,152
#define NF_OFF  ZERO_BYTES                    // 256-aligned

__device__ __forceinline__ u16 f2bf(float f) {
    uint32_t x = __float_as_uint(f);
    x += 0x7fffu + ((x >> 16) & 1u);          // round-to-nearest-even
    return (u16)(x >> 16);
}

__device__ __forceinline__ void gload16(const u16* g, u16* l) {
    __builtin_amdgcn_global_load_lds(
        (const __attribute__((address_space(1))) uint32_t*)g,
        (__attribute__((address_space(3))) uint32_t*)l, 16, 0, 0);
}

// ---------------- kernel 1: per-row stats + normalize + compact ----------------
__global__ __launch_bounds__(256) void stats_kernel(const float* __restrict__ wgt,
                                                    const float* __restrict__ mask,
                                                    u16* __restrict__ nf,
                                                    int* __restrict__ cnt) {
    int n = blockIdx.x;
    if (mask[n] == 0.0f) return;              // inactive filter: skip entirely
    int tid = threadIdx.x;
    const float4* row = (const float4*)(wgt + (size_t)n * DDIM);
    float4 v[9];
    float s = 0.f, ss = 0.f;
#pragma unroll
    for (int i = 0; i < 9; ++i) {
        v[i] = row[tid + 256 * i];
        s  += v[i].x + v[i].y + v[i].z + v[i].w;
        ss += v[i].x * v[i].x + v[i].y * v[i].y + v[i].z * v[i].z + v[i].w * v[i].w;
    }
#pragma unroll
    for (int o = 32; o > 0; o >>= 1) { s += __shfl_down(s, o); ss += __shfl_down(ss, o); }
    __shared__ float rs[4], rss[4];
    __shared__ float smean, sinv;
    __shared__ int   sidx;
    int w = tid >> 6, l = tid & 63;
    if (l == 0) { rs[w] = s; rss[w] = ss; }
    __syncthreads();
    if (tid == 0) {
        float S  = rs[0] + rs[1] + rs[2] + rs[3];
        float SS = rss[0] + rss[1] + rss[2] + rss[3];
        float mean = S / (float)DDIM;
        float var  = SS / (float)DDIM - mean * mean;
        float sd   = sqrtf(fmaxf(var, 0.f));
        if (sd == 0.f) sd = 1.f;              // reference: std==0 -> 1
        smean = mean; sinv = 1.f / sd;
        sidx = atomicAdd(cnt, 1);             // compacted slot (order irrelevant)
    }
    __syncthreads();
    float mean = smean, inv = sinv;
    u16* dst = nf + (size_t)sidx * DDIM;
#pragma unroll
    for (int i = 0; i < 9; ++i) {
        int e = (tid + 256 * i) * 4;
        uint32_t lo = (uint32_t)f2bf((v[i].x - mean) * inv) |
                      ((uint32_t)f2bf((v[i].y - mean) * inv) << 16);
        uint32_t hi = (uint32_t)f2bf((v[i].z - mean) * inv) |
                      ((uint32_t)f2bf((v[i].w - mean) * inv) << 16);
        uint2 u; u.x = lo; u.y = hi;
        *(uint2*)(dst + e) = u;
    }
}

// ---------------- kernel 2: triangle-tile bf16 MFMA GEMM, K-split ----------------
__global__ __launch_bounds__(256) void gemm_kernel(const u16* __restrict__ nf,
                                                   const int* __restrict__ cnt,
                                                   float* __restrict__ C) {
    int A = *cnt;
    int ntile = (A + 127) >> 7;
    int t = blockIdx.x, bi = 0, len = NTMAX;
    while (t >= len) { t -= len; --len; ++bi; }
    int bj = bi + t;
    if (bj >= ntile) return;                  // bi <= bj, so this covers both
    int r0 = bi << 7, c0 = bj << 7;
    bool diag = (bi == bj);

    __shared__ u16 lA[128 * BK];              // 8 KB
    __shared__ u16 lB[128 * BK];              // 8 KB

    int tid = threadIdx.x;
    int w = tid >> 6, l = tid & 63;
    int wr = w >> 1, wc = w & 1;              // 2x2 waves of 64x64
    int quad = l >> 4, m16 = l & 15;

    f32x4 acc[4][4] = {};

    // staging addresses: lane covers row (w*16 + l/4), cols (l%4)*8 .. +8
    int srow = (w << 4) + (l >> 2);
    int scol = (l & 3) << 3;
    const u16* gA0 = nf + (size_t)(r0 + srow) * DDIM + scol;
    const u16* gA1 = nf + (size_t)(r0 + 64 + srow) * DDIM + scol;
    const u16* gB0 = nf + (size_t)(c0 + srow) * DDIM + scol;
    const u16* gB1 = nf + (size_t)(c0 + 64 + srow) * DDIM + scol;
    u16* sA = lA + (w << 9);                  // wave-uniform LDS base (1 KB/wave)
    u16* sB = lB + (w << 9);

    int kbeg = blockIdx.y * KSLICE;
    for (int k0 = kbeg; k0 < kbeg + KSLICE; k0 += BK) {
        gload16(gA0 + k0, sA);
        gload16(gA1 + k0, sA + 2048);
        gload16(gB0 + k0, sB);
        gload16(gB1 + k0, sB + 2048);
        __syncthreads();
        bf16x8 af[4], bf[4];
#pragma unroll
        for (int mi = 0; mi < 4; ++mi)
            af[mi] = *(const bf16x8*)&lA[((wr << 6) + (mi << 4) + m16) * BK + (quad << 3)];
#pragma unroll
        for (int nj = 0; nj < 4; ++nj)
            bf[nj] = *(const bf16x8*)&lB[((wc << 6) + (nj << 4) + m16) * BK + (quad << 3)];
#pragma unroll
        for (int mi = 0; mi < 4; ++mi)
#pragma unroll
            for (int nj = 0; nj < 4; ++nj) {
                if (diag && (wr * 4 + mi) > (wc * 4 + nj)) continue; // strictly-lower blocks unused
                acc[mi][nj] = __builtin_amdgcn_mfma_f32_16x16x32_bf16(af[mi], bf[nj], acc[mi][nj], 0, 0, 0);
            }
        __syncthreads();
    }

    float* Ct = C + (size_t)blockIdx.x * (128 * 128);
#pragma unroll
    for (int mi = 0; mi < 4; ++mi)
#pragma unroll
        for (int nj = 0; nj < 4; ++nj) {
            if (diag && (wr * 4 + mi) > (wc * 4 + nj)) continue;
#pragma unroll
            for (int r = 0; r < 4; ++r) {
                // C/D layout: col = lane&15, row = quad*4 + r   [m89/m91 verified]
                int row = (wr << 6) + (mi << 4) + (quad << 2) + r;
                int col = (wc << 6) + (nj << 4) + m16;
                atomicAdd(&Ct[row * 128 + col], acc[mi][nj][r]);
            }
        }
}

// ---------------- kernel 3: square+mask+reduce over C tiles ----------------
__global__ __launch_bounds__(256) void reduce_kernel(const float* __restrict__ C,
                                                     const int* __restrict__ cnt,
                                                     float* __restrict__ sq) {
    int A = *cnt;
    int ntile = (A + 127) >> 7;
    int t = blockIdx.x, bi = 0, len = NTMAX;
    while (t >= len) { t -= len; --len; ++bi; }
    int bj = bi + t;
    if (bj >= ntile) return;
    const float* Ct = C + (size_t)blockIdx.x * (128 * 128);
    int r0 = bi << 7, c0 = bj << 7;
    float local = 0.f;
    for (int idx = threadIdx.x; idx < 128 * 128; idx += 256) {
        int i = r0 + (idx >> 7), j = c0 + (idx & 127);
        if (i < j && j < A) { float v = Ct[idx]; local += v * v; }
    }
#pragma unroll
    for (int o = 32; o > 0; o >>= 1) local += __shfl_down(local, o);
    __shared__ float ps[4];
    if ((threadIdx.x & 63) == 0) ps[threadIdx.x >> 6] = local;
    __syncthreads();
    if (threadIdx.x == 0) atomicAdd(sq, ps[0] + ps[1] + ps[2] + ps[3]);
}

// ---------------- kernel 4: finalize ----------------
__global__ void final_kernel(const int* __restrict__ cnt, const float* __restrict__ sq,
                             float* __restrict__ out) {
    long long A = *cnt;
    long long na = A * (A - 1) / 2;           // = sum of strict-upper mask products (exact)
    double loss = 0.0;
    if (na > 0) loss = (double)(*sq) / ((double)DDIM * (double)DDIM) / (double)na;
    out[0] = (float)loss;
}

extern "C" void kernel_launch(void* const* d_in, const int* in_sizes, int n_in,
                              void* d_out, int out_size, void* d_ws, size_t ws_size,
                              hipStream_t stream) {
    (void)in_sizes; (void)n_in; (void)out_size; (void)ws_size;
    const float* wgt  = (const float*)d_in[0];
    const float* mask = (const float*)d_in[1];
    float* out = (float*)d_out;
    char*  ws  = (char*)d_ws;

    int*   cnt = (int*)ws;
    float* sq  = (float*)(ws + 4);
    float* C   = (float*)(ws + C_OFF);
    u16*   nf  = (u16*)(ws + NF_OFF);

    hipMemsetAsync(ws, 0, ZERO_BYTES, stream);
    stats_kernel<<<NROWS, 256, 0, stream>>>(wgt, mask, nf, cnt);
    gemm_kernel<<<dim3(NTRI, SLICES), 256, 0, stream>>>(nf, cnt, C);
    reduce_kernel<<<NTRI, 256, 0, stream>>>(C, cnt, sq);
    final_kernel<<<1, 1, 0, stream>>>(cnt, sq, out);
}

// Round 2
// 168.079 us; speedup vs baseline: 1.1812x; 1.1812x over previous
//
#include <hip/hip_runtime.h>
#include <stdint.h>

#define NROWS 2048
#define DDIM  9216
#define T64   32                      // max 64-row tiles per dim (2048/64)
#define NTRI  528                     // T64*(T64+1)/2 triangle tiles
#define WKLEN 2304                    // DDIM/4 : K-range per wave
#define WKIT  36                      // WKLEN/64 : K iterations per wave

typedef unsigned short u16;
typedef __bf16 bf16x8 __attribute__((ext_vector_type(8)));
typedef float  f32x4  __attribute__((ext_vector_type(4)));

// ws layout: [0] int cnt, [4] float sq, [256..) u16 nf[2048][9216] (37.75 MB)
#define NF_OFF 256

__device__ __forceinline__ u16 f2bf(float f) {
    uint32_t x = __float_as_uint(f);
    x += 0x7fffu + ((x >> 16) & 1u);          // round-to-nearest-even
    return (u16)(x >> 16);
}

__device__ __forceinline__ void gload16(const u16* g, u16* l) {
    __builtin_amdgcn_global_load_lds(
        (const __attribute__((address_space(1))) uint32_t*)g,
        (__attribute__((address_space(3))) uint32_t*)l, 16, 0, 0);
}

// ---------------- kernel 1: per-row stats + normalize + compact ----------------
__global__ __launch_bounds__(256) void stats_kernel(const float* __restrict__ wgt,
                                                    const float* __restrict__ mask,
                                                    u16* __restrict__ nf,
                                                    int* __restrict__ cnt) {
    int n = blockIdx.x;
    if (mask[n] == 0.0f) return;              // inactive filter: skip entirely
    int tid = threadIdx.x;
    const float4* row = (const float4*)(wgt + (size_t)n * DDIM);
    float4 v[9];
    float s = 0.f, ss = 0.f;
#pragma unroll
    for (int i = 0; i < 9; ++i) {
        v[i] = row[tid + 256 * i];
        s  += v[i].x + v[i].y + v[i].z + v[i].w;
        ss += v[i].x * v[i].x + v[i].y * v[i].y + v[i].z * v[i].z + v[i].w * v[i].w;
    }
#pragma unroll
    for (int o = 32; o > 0; o >>= 1) { s += __shfl_down(s, o); ss += __shfl_down(ss, o); }
    __shared__ float rs[4], rss[4];
    __shared__ float smean, sinv;
    __shared__ int   sidx;
    int w = tid >> 6, l = tid & 63;
    if (l == 0) { rs[w] = s; rss[w] = ss; }
    __syncthreads();
    if (tid == 0) {
        float S  = rs[0] + rs[1] + rs[2] + rs[3];
        float SS = rss[0] + rss[1] + rss[2] + rss[3];
        float mean = S / (float)DDIM;
        float var  = SS / (float)DDIM - mean * mean;
        float sd   = sqrtf(fmaxf(var, 0.f));
        if (sd == 0.f) sd = 1.f;              // reference: std==0 -> 1
        smean = mean; sinv = 1.f / sd;
        sidx = atomicAdd(cnt, 1);             // compacted slot (order irrelevant)
    }
    __syncthreads();
    float mean = smean, inv = sinv;
    u16* dst = nf + (size_t)sidx * DDIM;
#pragma unroll
    for (int i = 0; i < 9; ++i) {
        int e = (tid + 256 * i) * 4;
        uint32_t lo = (uint32_t)f2bf((v[i].x - mean) * inv) |
                      ((uint32_t)f2bf((v[i].y - mean) * inv) << 16);
        uint32_t hi = (uint32_t)f2bf((v[i].z - mean) * inv) |
                      ((uint32_t)f2bf((v[i].w - mean) * inv) << 16);
        uint2 u; u.x = lo; u.y = hi;
        *(uint2*)(dst + e) = u;
    }
}

// ---------------- kernel 2: fused 64x64-tile GEMM + square-reduce ----------------
// Block = 4 waves. Each wave owns a PRIVATE K-quarter and PRIVATE 16 KB LDS
// buffers -> no __syncthreads in the K-loop (wave-local vmcnt(0) only).
// Epilogue combines the 4 partial 64x64 accumulators in LDS, squares, masks
// (strict upper triangle, j < A), and atomicAdds one scalar per wave.
template<bool DIAG>
__device__ __forceinline__ void kloop36(const u16* pA, const u16* pB,
                                        u16* bufA, u16* bufB,
                                        int m16, int quad, f32x4 acc[4][4]) {
    const u16* rB = DIAG ? bufA : bufB;
    for (int it = 0; it < WKIT; ++it) {
        const u16* a = pA + it * 64;
#pragma unroll
        for (int i = 0; i < 8; ++i) gload16(a + i * 8 * DDIM, bufA + i * 512);
        if (!DIAG) {
            const u16* b = pB + it * 64;
#pragma unroll
            for (int i = 0; i < 8; ++i) gload16(b + i * 8 * DDIM, bufB + i * 512);
        }
        // wait for this wave's LDS-DMA only; lgkm deps handled by compiler.
        __builtin_amdgcn_s_waitcnt(0x0F70);   // vmcnt(0), lgkm=15, exp=7
        __builtin_amdgcn_wave_barrier();
#pragma unroll
        for (int kk = 0; kk < 2; ++kk) {
            bf16x8 af[4], bf[4];
#pragma unroll
            for (int fm = 0; fm < 4; ++fm)
                af[fm] = *(const bf16x8*)&bufA[(fm * 16 + m16) * 64 + kk * 32 + quad * 8];
#pragma unroll
            for (int fn = 0; fn < 4; ++fn)
                bf[fn] = *(const bf16x8*)&rB[(fn * 16 + m16) * 64 + kk * 32 + quad * 8];
#pragma unroll
            for (int fm = 0; fm < 4; ++fm)
#pragma unroll
                for (int fn = 0; fn < 4; ++fn)
                    acc[fm][fn] = __builtin_amdgcn_mfma_f32_16x16x32_bf16(
                        af[fm], bf[fn], acc[fm][fn], 0, 0, 0);
        }
        __builtin_amdgcn_wave_barrier();      // keep next stage's LDS writes after reads
    }
}

__global__ __launch_bounds__(256) void gemm_kernel(const u16* __restrict__ nf,
                                                   const int* __restrict__ cnt,
                                                   float* __restrict__ sq) {
    __shared__ u16 ls[32768];                 // 64 KB: 4 waves x (A 8KB + B 8KB)
    int A = *cnt;
    int nt = (A + 63) >> 6;
    int t = blockIdx.x, bi = 0, len = T64;
    while (t >= len) { t -= len; --len; ++bi; }
    int bj = bi + t;
    if (bj >= nt) return;                     // bi <= bj
    int r0 = bi << 6, c0 = bj << 6;
    int tid = threadIdx.x, l = tid & 63, w = tid >> 6;
    int quad = l >> 4, m16 = l & 15;
    int kbeg = w * WKLEN;
    const u16* pA = nf + (size_t)(r0 + (l >> 3)) * DDIM + ((l & 7) << 3) + kbeg;
    const u16* pB = nf + (size_t)(c0 + (l >> 3)) * DDIM + ((l & 7) << 3) + kbeg;
    u16* bufA = ls + w * 8192;                // 8 KB = 64 rows x 64 u16 (BK=64)
    u16* bufB = bufA + 4096;
    f32x4 acc[4][4] = {};
    if (bi == bj) kloop36<true >(pA, pB, bufA, bufB, m16, quad, acc);
    else          kloop36<false>(pA, pB, bufA, bufB, m16, quad, acc);

    // ---- epilogue: park partials in own wave's LDS region (frag-major) ----
    float* fw = (float*)ls + w * 4096;        // 16 KB per wave, overlays own bufs
#pragma unroll
    for (int fm = 0; fm < 4; ++fm)
#pragma unroll
        for (int fn = 0; fn < 4; ++fn)
            *(f32x4*)&fw[(fm * 4 + fn) * 256 + l * 4] = acc[fm][fn];
    __syncthreads();
    const float* fs = (const float*)ls;
    float local = 0.f;
#pragma unroll
    for (int i = 0; i < 4; ++i) {
        int o = tid * 4 + i * 1024;           // offset within a wave region
        f32x4 v = *(const f32x4*)&fs[o];
        v += *(const f32x4*)&fs[o + 4096];
        v += *(const f32x4*)&fs[o + 8192];
        v += *(const f32x4*)&fs[o + 12288];
        int f = o >> 8, lk = (o >> 2) & 63;   // frag id, lane id; o&3 = reg r
        int row = ((f >> 2) << 4) + ((lk >> 4) << 2);   // + r
        int col = ((f & 3) << 4) + (lk & 15);
        int gj = c0 + col;
        if (gj < A) {
#pragma unroll
            for (int r = 0; r < 4; ++r) {
                int gi = r0 + row + r;
                if (gi < gj) local += v[r] * v[r];
            }
        }
    }
#pragma unroll
    for (int o = 32; o > 0; o >>= 1) local += __shfl_down(local, o);
    if (l == 0) atomicAdd(sq, local);         // 4 atomics per active block
}

// ---------------- kernel 3: finalize ----------------
__global__ void final_kernel(const int* __restrict__ cnt, const float* __restrict__ sq,
                             float* __restrict__ out) {
    long long A = *cnt;
    long long na = A * (A - 1) / 2;           // sum of strict-upper mask products
    double loss = 0.0;
    if (na > 0) loss = (double)(*sq) / ((double)DDIM * (double)DDIM) / (double)na;
    out[0] = (float)loss;
}

extern "C" void kernel_launch(void* const* d_in, const int* in_sizes, int n_in,
                              void* d_out, int out_size, void* d_ws, size_t ws_size,
                              hipStream_t stream) {
    (void)in_sizes; (void)n_in; (void)out_size; (void)ws_size;
    const float* wgt  = (const float*)d_in[0];
    const float* mask = (const float*)d_in[1];
    float* out = (float*)d_out;
    char*  ws  = (char*)d_ws;

    int*   cnt = (int*)ws;
    float* sq  = (float*)(ws + 4);
    u16*   nf  = (u16*)(ws + NF_OFF);

    hipMemsetAsync(ws, 0, 256, stream);
    stats_kernel<<<NROWS, 256, 0, stream>>>(wgt, mask, nf, cnt);
    gemm_kernel<<<NTRI, 256, 0, stream>>>(nf, cnt, sq);
    final_kernel<<<1, 1, 0, stream>>>(cnt, sq, out);
}